// Round 5
// baseline (1845.066 us; speedup 1.0000x reference)
//
#include <hip/hip_runtime.h>
#include <stdint.h>

typedef __attribute__((ext_vector_type(8)))  short   short8;
typedef __attribute__((ext_vector_type(8)))  unsigned short ushort8;
typedef __attribute__((ext_vector_type(8)))  __bf16  bf16x8;
typedef __attribute__((ext_vector_type(4)))  float   floatx4;
typedef __attribute__((ext_vector_type(4)))  unsigned short ushort4v;

#define AS1 __attribute__((address_space(1)))
#define AS3 __attribute__((address_space(3)))

__device__ __forceinline__ unsigned short f2bf(float f) {
  unsigned u = __builtin_bit_cast(unsigned, f);
  u = (u + 0x7FFFu + ((u >> 16) & 1u)) >> 16;   // RNE
  return (unsigned short)u;
}

// ---------------- f32 -> bf16 convert (n multiple of 1024) ----------------
__global__ __launch_bounds__(256) void convert_bf16(const float* __restrict__ src,
                                                    unsigned short* __restrict__ dst,
                                                    int n) {
  int i = (blockIdx.x * 256 + threadIdx.x) * 4;
  if (i >= n) return;
  float4 v = *(const float4*)(src + i);
  ushort4v o;
  o.x = f2bf(v.x); o.y = f2bf(v.y); o.z = f2bf(v.z); o.w = f2bf(v.w);
  *(ushort4v*)(dst + i) = o;
}

// ---------------- int64-vs-int32 id layout detection ----------------
__global__ __launch_bounds__(256) void detect_i64(const int* __restrict__ idbuf,
                                                  int* __restrict__ flag) {
  int v = 0;
  for (int i = threadIdx.x; i < 2048; i += 256) v |= idbuf[2 * i + 1];
  if (v != 0) atomicOr(flag, 1);
}

// ---------------- gather rows of emb -> bf16 x ----------------
__global__ __launch_bounds__(256) void gather_embed(const int* __restrict__ ids,
                                                    const float* __restrict__ emb,
                                                    unsigned short* __restrict__ xbf,
                                                    const int* __restrict__ flag) {
  int i = blockIdx.x;                      // 0..4095 (b*256+s)
  int row = (*flag != 0) ? ids[i] : ids[2 * i];   // int32 vs int64 layout
  const float* src = emb + (size_t)row * 1024 + threadIdx.x * 4;
  float4 v = *(const float4*)src;
  ushort4v o;
  o.x = f2bf(v.x); o.y = f2bf(v.y); o.z = f2bf(v.z); o.w = f2bf(v.w);
  *(ushort4v*)(xbf + (size_t)i * 1024 + threadIdx.x * 4) = o;
}

// ---------------- bf16 GEMM  C[rowmap(r),N] = A[r,K] * B[N,K]^T  (f32 out) ----
// rowmap: 0 identity; 1: r -> (r&255)*16 + (r>>8)   [b*256+s -> s*16+b]
//         2: r -> (r&15)*256 + (r>>4)               [t*16+b  -> b*256+t]
__global__ __launch_bounds__(256) void gemm_bt(const unsigned short* __restrict__ A,
                                               const unsigned short* __restrict__ B,
                                               float* __restrict__ C,
                                               int M, int N, int K, int rowmap) {
  __shared__ unsigned short lA[128 * 64];
  __shared__ unsigned short lB[128 * 64];
  const int nwg  = gridDim.x;
  const int wgid = blockIdx.x;
  const int q    = nwg >> 3;                       // XCD-aware swizzle (nwg % 8 == 0)
  const int swz  = (wgid & 7) * q + (wgid >> 3);
  const int ntx  = N >> 7;
  const int bx   = swz % ntx;
  const int by   = swz / ntx;
  const int tid  = threadIdx.x;
  const int lane = tid & 63;
  const int w    = tid >> 6;
  const int wr   = w >> 1, wc = w & 1;

  floatx4 acc[4][4];
#pragma unroll
  for (int m = 0; m < 4; ++m)
#pragma unroll
    for (int n = 0; n < 4; ++n) acc[m][n] = (floatx4){0.f, 0.f, 0.f, 0.f};

  const size_t rowA0 = (size_t)by * 128;
  const size_t colB0 = (size_t)bx * 128;

  for (int k0 = 0; k0 < K; k0 += 64) {
#pragma unroll
    for (int p = 0; p < 4; ++p) {
      int cc = p * 256 + tid;       // 16B chunk id, 0..1023
      int r  = cc >> 3;             // tile row 0..127
      int c8 = cc & 7;              // 16B chunk within row
      const unsigned short* srcA = A + (rowA0 + r) * K + k0 + c8 * 8;
      const unsigned short* srcB = B + (colB0 + r) * K + k0 + c8 * 8;
      __builtin_amdgcn_global_load_lds((const AS1 unsigned int*)srcA,
                                       (AS3 unsigned int*)&lA[cc * 8], 16, 0, 0);
      __builtin_amdgcn_global_load_lds((const AS1 unsigned int*)srcB,
                                       (AS3 unsigned int*)&lB[cc * 8], 16, 0, 0);
    }
    __syncthreads();
#pragma unroll
    for (int kk = 0; kk < 2; ++kk) {
      const int kofs = kk * 32 + (lane >> 4) * 8;
      bf16x8 af[4], bfv[4];
#pragma unroll
      for (int m = 0; m < 4; ++m) {
        int r = wr * 64 + m * 16 + (lane & 15);
        af[m] = *(const bf16x8*)&lA[r * 64 + kofs];
      }
#pragma unroll
      for (int n = 0; n < 4; ++n) {
        int r = wc * 64 + n * 16 + (lane & 15);
        bfv[n] = *(const bf16x8*)&lB[r * 64 + kofs];
      }
#pragma unroll
      for (int m = 0; m < 4; ++m)
#pragma unroll
        for (int n = 0; n < 4; ++n)
          acc[m][n] = __builtin_amdgcn_mfma_f32_16x16x32_bf16(af[m], bfv[n], acc[m][n], 0, 0, 0);
    }
    __syncthreads();
  }

#pragma unroll
  for (int m = 0; m < 4; ++m) {
#pragma unroll
    for (int j = 0; j < 4; ++j) {
      size_t row = rowA0 + wr * 64 + m * 16 + ((lane >> 4) * 4 + j);
      size_t orow = (rowmap == 0) ? row
                  : (rowmap == 1) ? ((row & 255) * 16 + (row >> 8))
                                  : ((row & 15) * 256 + (row >> 4));
      float* crow = C + orow * (size_t)N + colB0 + wc * 64 + (lane & 15);
#pragma unroll
      for (int n = 0; n < 4; ++n) crow[n * 16] = acc[m][n][j];
    }
  }
}

// ---------------- recurrence via MFMA: h_t = tanh(xin_t + h_{t-1} @ w_hh^T) ----
// 64 WGs x 64 threads (1 wave each). Wave computes D[16 batch][16 out] with
// K=1024 as 32 chained mfma_f32_16x16x32_bf16. Weights = 32 B-frags resident
// in VGPRs (128 VGPRs, 512 budget via launch_bounds(64,1)).
// h state: bf16 [t][b][out] step buffer, NaN-armed (0xFF), write-once.
// Sync: the A-frag load IS the poll; a NaN sentinel propagates through the
// MFMA into acc -> redo. No flags, no drains, no check storms.
__global__ __launch_bounds__(64, 1) void rnn_mfma(const float* __restrict__ xin,        // [256*16][1024] f32 ([t*16+b])
                                                  const unsigned short* __restrict__ whh,// [1024][1024] bf16
                                                  unsigned short* __restrict__ hst) {    // [256][16*1024] bf16, NaN-armed
  const int lane = threadIdx.x;            // 0..63
  const int n    = lane & 15;              // out offset within tile / A row (batch)
  const int g    = lane >> 4;              // 0..3 (k-group)
  const int out_base = blockIdx.x * 16;

  // B-fragments: wb[ks][j] = w_hh[out_base+n][g*8 + j + 32*ks]
  bf16x8 wb[32];
#pragma unroll
  for (int ks = 0; ks < 32; ++ks)
    wb[ks] = *(const bf16x8*)&whh[(size_t)(out_base + n) * 1024 + g * 8 + ks * 32];

  for (int t = 0; t < 256; ++t) {
    // prefetch xin for the tail: batch = g*4+jj, out = out_base+n
    float xi[4];
#pragma unroll
    for (int jj = 0; jj < 4; ++jj)
      xi[jj] = xin[(size_t)(t * 16 + g * 4 + jj) * 1024 + out_base + n];

    floatx4 s4 = (floatx4){0.f, 0.f, 0.f, 0.f};
    if (t > 0) {
      // A-frag base: h_{t-1}[batch = n][k = g*8 + 32*ks .. +8]
      const unsigned long long* src = (const unsigned long long*)
          &hst[(size_t)(t - 1) * 16384 + (size_t)n * 1024 + g * 8];
      for (;;) {
        unsigned long long lo[32], hi[32];
#pragma unroll
        for (int ks = 0; ks < 32; ++ks) {    // 64B stride per ks (32 elems)
          lo[ks] = __hip_atomic_load(src + ks * 8 + 0, __ATOMIC_RELAXED, __HIP_MEMORY_SCOPE_AGENT);
          hi[ks] = __hip_atomic_load(src + ks * 8 + 1, __ATOMIC_RELAXED, __HIP_MEMORY_SCOPE_AGENT);
        }
        floatx4 a0 = (floatx4){0,0,0,0}, a1 = (floatx4){0,0,0,0};
        floatx4 a2 = (floatx4){0,0,0,0}, a3 = (floatx4){0,0,0,0};
#pragma unroll
        for (int ks = 0; ks < 32; ++ks) {
          bf16x8 af = __builtin_bit_cast(bf16x8, (ulonglong2){lo[ks], hi[ks]});
          if      ((ks & 3) == 0) a0 = __builtin_amdgcn_mfma_f32_16x16x32_bf16(af, wb[ks], a0, 0, 0, 0);
          else if ((ks & 3) == 1) a1 = __builtin_amdgcn_mfma_f32_16x16x32_bf16(af, wb[ks], a1, 0, 0, 0);
          else if ((ks & 3) == 2) a2 = __builtin_amdgcn_mfma_f32_16x16x32_bf16(af, wb[ks], a2, 0, 0, 0);
          else                    a3 = __builtin_amdgcn_mfma_f32_16x16x32_bf16(af, wb[ks], a3, 0, 0, 0);
        }
        s4 = (a0 + a1) + (a2 + a3);
        int bad = __builtin_isnan(s4[0]) | __builtin_isnan(s4[1]) |
                  __builtin_isnan(s4[2]) | __builtin_isnan(s4[3]);
        if (!__any(bad)) break;             // all 2048 source values were valid
      }
    }

    // tail: h = tanh(s); D rows = batches g*4+jj, col = out_base+n
    float hv[4];
#pragma unroll
    for (int jj = 0; jj < 4; ++jj) {
      float s = s4[jj] + xi[jj];
      float e = __expf(2.0f * s);
      hv[jj] = 1.0f - 2.0f * __builtin_amdgcn_rcpf(e + 1.0f);
    }
    // pair-pack with lane^1 so each store is a full dword (2 adjacent outs)
    float pv[4];
#pragma unroll
    for (int jj = 0; jj < 4; ++jj) pv[jj] = __shfl_xor(hv[jj], 1);
    const int ev = (lane & 1) == 0;
    const int jA = ev ? 0 : 2, jB = ev ? 1 : 3;
    unsigned dA = ev ? ((unsigned)f2bf(hv[jA]) | ((unsigned)f2bf(pv[jA]) << 16))
                     : ((unsigned)f2bf(pv[jA]) | ((unsigned)f2bf(hv[jA]) << 16));
    unsigned dB = ev ? ((unsigned)f2bf(hv[jB]) | ((unsigned)f2bf(pv[jB]) << 16))
                     : ((unsigned)f2bf(pv[jB]) | ((unsigned)f2bf(hv[jB]) << 16));
    unsigned* rowA = (unsigned*)&hst[(size_t)t * 16384 + (size_t)(g * 4 + jA) * 1024 + out_base + (n & ~1)];
    unsigned* rowB = (unsigned*)&hst[(size_t)t * 16384 + (size_t)(g * 4 + jB) * 1024 + out_base + (n & ~1)];
    __hip_atomic_store(rowA, dA, __ATOMIC_RELAXED, __HIP_MEMORY_SCOPE_AGENT);
    __hip_atomic_store(rowB, dB, __ATOMIC_RELAXED, __HIP_MEMORY_SCOPE_AGENT);
  }
}

// ---------------- host launch ----------------
extern "C" void kernel_launch(void* const* d_in, const int* in_sizes, int n_in,
                              void* d_out, int out_size, void* d_ws, size_t ws_size,
                              hipStream_t stream) {
  const int*   ids  = (const int*)d_in[0];     // [16,256]
  const float* emb  = (const float*)d_in[1];   // [32000,1024]
  const float* w_hx = (const float*)d_in[2];   // [1024,1024]
  const float* w_hh = (const float*)d_in[3];   // [1024,1024]
  const float* w_yh = (const float*)d_in[4];   // [32000,1024]
  float*       out  = (float*)d_out;           // [16,256,32000]

  const int B = 16, S = 256, H = 1024, V = 32000;
  const int BS = B * S;

  char*  ws  = (char*)d_ws;
  size_t off = 0;
  auto alloc = [&](size_t bytes) {
    size_t cur = off;
    off += (bytes + 255) & ~(size_t)255;
    return (void*)(ws + cur);
  };

  unsigned short* whx_bf = (unsigned short*)alloc((size_t)H * H * 2);
  unsigned short* whh_bf = (unsigned short*)alloc((size_t)H * H * 2);
  unsigned short* wyh_bf = (unsigned short*)alloc((size_t)V * H * 2);
  unsigned short* x_bf   = (unsigned short*)alloc((size_t)BS * H * 2);
  float*          xin    = (float*)alloc((size_t)BS * H * 4);   // [t*16+b][H]
  unsigned short* hst    = (unsigned short*)alloc((size_t)BS * H * 2); // [t][b][H]
  int*            dflag  = (int*)alloc(256);

  // NaN-arm the step buffer every call (write-once data-as-flag; replay-safe).
  hipMemsetAsync(hst, 0xFF, (size_t)BS * H * 2, stream);
  hipMemsetAsync(dflag, 0, 256, stream);

  detect_i64<<<dim3(1), dim3(256), 0, stream>>>(ids, dflag);
  convert_bf16<<<dim3((H * H) / 1024), dim3(256), 0, stream>>>(w_hx, whx_bf, H * H);
  convert_bf16<<<dim3((H * H) / 1024), dim3(256), 0, stream>>>(w_hh, whh_bf, H * H);
  convert_bf16<<<dim3((V * H) / 1024), dim3(256), 0, stream>>>(w_yh, wyh_bf, V * H);
  gather_embed<<<dim3(BS), dim3(256), 0, stream>>>(ids, emb, x_bf, dflag);

  // xin[s*16+b] = x[b*256+s] @ w_hx^T : rowmap=1
  gemm_bt<<<dim3((BS / 128) * (H / 128)), dim3(256), 0, stream>>>(x_bf, whx_bf, xin, BS, H, H, 1);

  // sequential recurrence: 64 waves, MFMA, data-as-flag(NaN) sync
  rnn_mfma<<<dim3(64), dim3(64), 0, stream>>>(xin, whh_bf, hst);

  // logits[b*256+t] = h[t*16+b] @ w_yh^T : rowmap=2
  gemm_bt<<<dim3((BS / 128) * (V / 128)), dim3(256), 0, stream>>>(hst, wyh_bf, out, BS, V, H, 2);
}

// Round 6
// 1720.038 us; speedup vs baseline: 1.0727x; 1.0727x over previous
//
#include <hip/hip_runtime.h>
#include <stdint.h>

typedef __attribute__((ext_vector_type(8)))  short   short8;
typedef __attribute__((ext_vector_type(8)))  unsigned short ushort8;
typedef __attribute__((ext_vector_type(8)))  __bf16  bf16x8;
typedef __attribute__((ext_vector_type(4)))  float   floatx4;
typedef __attribute__((ext_vector_type(4)))  unsigned short ushort4v;

#define AS1 __attribute__((address_space(1)))
#define AS3 __attribute__((address_space(3)))

__device__ __forceinline__ unsigned short f2bf(float f) {
  unsigned u = __builtin_bit_cast(unsigned, f);
  u = (u + 0x7FFFu + ((u >> 16) & 1u)) >> 16;   // RNE
  return (unsigned short)u;
}

// ---------------- f32 -> bf16 convert (n multiple of 1024) ----------------
__global__ __launch_bounds__(256) void convert_bf16(const float* __restrict__ src,
                                                    unsigned short* __restrict__ dst,
                                                    int n) {
  int i = (blockIdx.x * 256 + threadIdx.x) * 4;
  if (i >= n) return;
  float4 v = *(const float4*)(src + i);
  ushort4v o;
  o.x = f2bf(v.x); o.y = f2bf(v.y); o.z = f2bf(v.z); o.w = f2bf(v.w);
  *(ushort4v*)(dst + i) = o;
}

// ---------------- int64-vs-int32 id layout detection ----------------
__global__ __launch_bounds__(256) void detect_i64(const int* __restrict__ idbuf,
                                                  int* __restrict__ flag) {
  int v = 0;
  for (int i = threadIdx.x; i < 2048; i += 256) v |= idbuf[2 * i + 1];
  if (v != 0) atomicOr(flag, 1);
}

// ---------------- gather rows of emb -> bf16 x ----------------
__global__ __launch_bounds__(256) void gather_embed(const int* __restrict__ ids,
                                                    const float* __restrict__ emb,
                                                    unsigned short* __restrict__ xbf,
                                                    const int* __restrict__ flag) {
  int i = blockIdx.x;                      // 0..4095 (b*256+s)
  int row = (*flag != 0) ? ids[i] : ids[2 * i];   // int32 vs int64 layout
  const float* src = emb + (size_t)row * 1024 + threadIdx.x * 4;
  float4 v = *(const float4*)src;
  ushort4v o;
  o.x = f2bf(v.x); o.y = f2bf(v.y); o.z = f2bf(v.z); o.w = f2bf(v.w);
  *(ushort4v*)(xbf + (size_t)i * 1024 + threadIdx.x * 4) = o;
}

// ---------------- bf16 GEMM  C[rowmap(r),N] = A[r,K] * B[N,K]^T  (f32 out) ----
// rowmap: 0 identity; 1: r -> (r&255)*16 + (r>>8)   [b*256+s -> s*16+b]
//         2: r -> (r&15)*256 + (r>>4)               [t*16+b  -> b*256+t]
__global__ __launch_bounds__(256) void gemm_bt(const unsigned short* __restrict__ A,
                                               const unsigned short* __restrict__ B,
                                               float* __restrict__ C,
                                               int M, int N, int K, int rowmap) {
  __shared__ unsigned short lA[128 * 64];
  __shared__ unsigned short lB[128 * 64];
  const int nwg  = gridDim.x;
  const int wgid = blockIdx.x;
  const int q    = nwg >> 3;                       // XCD-aware swizzle (nwg % 8 == 0)
  const int swz  = (wgid & 7) * q + (wgid >> 3);
  const int ntx  = N >> 7;
  const int bx   = swz % ntx;
  const int by   = swz / ntx;
  const int tid  = threadIdx.x;
  const int lane = tid & 63;
  const int w    = tid >> 6;
  const int wr   = w >> 1, wc = w & 1;

  floatx4 acc[4][4];
#pragma unroll
  for (int m = 0; m < 4; ++m)
#pragma unroll
    for (int n = 0; n < 4; ++n) acc[m][n] = (floatx4){0.f, 0.f, 0.f, 0.f};

  const size_t rowA0 = (size_t)by * 128;
  const size_t colB0 = (size_t)bx * 128;

  for (int k0 = 0; k0 < K; k0 += 64) {
#pragma unroll
    for (int p = 0; p < 4; ++p) {
      int cc = p * 256 + tid;       // 16B chunk id, 0..1023
      int r  = cc >> 3;             // tile row 0..127
      int c8 = cc & 7;              // 16B chunk within row
      const unsigned short* srcA = A + (rowA0 + r) * K + k0 + c8 * 8;
      const unsigned short* srcB = B + (colB0 + r) * K + k0 + c8 * 8;
      __builtin_amdgcn_global_load_lds((const AS1 unsigned int*)srcA,
                                       (AS3 unsigned int*)&lA[cc * 8], 16, 0, 0);
      __builtin_amdgcn_global_load_lds((const AS1 unsigned int*)srcB,
                                       (AS3 unsigned int*)&lB[cc * 8], 16, 0, 0);
    }
    __syncthreads();
#pragma unroll
    for (int kk = 0; kk < 2; ++kk) {
      const int kofs = kk * 32 + (lane >> 4) * 8;
      bf16x8 af[4], bfv[4];
#pragma unroll
      for (int m = 0; m < 4; ++m) {
        int r = wr * 64 + m * 16 + (lane & 15);
        af[m] = *(const bf16x8*)&lA[r * 64 + kofs];
      }
#pragma unroll
      for (int n = 0; n < 4; ++n) {
        int r = wc * 64 + n * 16 + (lane & 15);
        bfv[n] = *(const bf16x8*)&lB[r * 64 + kofs];
      }
#pragma unroll
      for (int m = 0; m < 4; ++m)
#pragma unroll
        for (int n = 0; n < 4; ++n)
          acc[m][n] = __builtin_amdgcn_mfma_f32_16x16x32_bf16(af[m], bfv[n], acc[m][n], 0, 0, 0);
    }
    __syncthreads();
  }

#pragma unroll
  for (int m = 0; m < 4; ++m) {
#pragma unroll
    for (int j = 0; j < 4; ++j) {
      size_t row = rowA0 + wr * 64 + m * 16 + ((lane >> 4) * 4 + j);
      size_t orow = (rowmap == 0) ? row
                  : (rowmap == 1) ? ((row & 255) * 16 + (row >> 8))
                                  : ((row & 15) * 256 + (row >> 4));
      float* crow = C + orow * (size_t)N + colB0 + wc * 64 + (lane & 15);
#pragma unroll
      for (int n = 0; n < 4; ++n) crow[n * 16] = acc[m][n][j];
    }
  }
}

// ---------------- recurrence via MFMA: h_t = tanh(xin_t + h_{t-1} @ w_hh^T) ----
// 64 WGs x 4 waves. WG og computes h_t[b=0..15][og*16 .. og*16+16).
// Wave w owns K-quarter [w*256, (w+1)*256): 8 B-frags resident (32 VGPRs),
// retry body = 16 u64 agent loads + 8 MFMA (NaN sentinel propagates into acc).
// Partials summed via LDS red[2][4][64] (double-buffered: a wave can only
// reach its t+1 red-write after h_t is fully published, which requires this
// WG's wave 0 to have consumed red at t -> one barrier per step suffices).
// h state: bf16 [t][b][out], NaN-armed (0xFF), write-once, agent-scope.
__global__ __launch_bounds__(256, 1) void rnn_mfma(const float* __restrict__ xin,         // [t*16+b][1024] f32
                                                   const unsigned short* __restrict__ whh,// [1024][1024] bf16
                                                   unsigned short* __restrict__ hst) {    // [256][16*1024] bf16, NaN-armed
  const int tid  = threadIdx.x;
  const int lane = tid & 63;
  const int w    = tid >> 6;        // 0..3: K-quarter
  const int n    = lane & 15;       // out col within tile / A batch row
  const int g    = lane >> 4;       // 0..3: k-subgroup within 32-wide MFMA step
  const int out_base = blockIdx.x * 16;

  __shared__ floatx4 red[2][4][64];

  // B-frags: wb[ks][j] = w_hh[out_base+n][w*256 + ks*32 + g*8 + j]
  bf16x8 wb[8];
#pragma unroll
  for (int ks = 0; ks < 8; ++ks)
    wb[ks] = *(const bf16x8*)&whh[(size_t)(out_base + n) * 1024 + w * 256 + ks * 32 + g * 8];

  for (int t = 0; t < 256; ++t) {
    // wave 0 prefetches xin for the tail: batch = g*4+jj, out = out_base+n
    float xi[4];
    if (w == 0) {
#pragma unroll
      for (int jj = 0; jj < 4; ++jj)
        xi[jj] = xin[(size_t)(t * 16 + g * 4 + jj) * 1024 + out_base + n];
    }

    floatx4 s4 = (floatx4){0.f, 0.f, 0.f, 0.f};
    if (t > 0) {
      // A-frag base: h_{t-1}[batch=n][k = w*256 + ks*32 + g*8 .. +8]
      const unsigned long long* src = (const unsigned long long*)
          &hst[(size_t)(t - 1) * 16384 + (size_t)n * 1024 + w * 256 + g * 8];
      for (;;) {
        unsigned long long lo[8], hi[8];
#pragma unroll
        for (int ks = 0; ks < 8; ++ks) {     // 64B (8 u64) stride per ks
          lo[ks] = __hip_atomic_load(src + ks * 8 + 0, __ATOMIC_RELAXED, __HIP_MEMORY_SCOPE_AGENT);
          hi[ks] = __hip_atomic_load(src + ks * 8 + 1, __ATOMIC_RELAXED, __HIP_MEMORY_SCOPE_AGENT);
        }
        floatx4 a0 = (floatx4){0,0,0,0}, a1 = (floatx4){0,0,0,0};
#pragma unroll
        for (int ks = 0; ks < 8; ++ks) {
          bf16x8 af = __builtin_bit_cast(bf16x8, (ulonglong2){lo[ks], hi[ks]});
          if (ks & 1) a1 = __builtin_amdgcn_mfma_f32_16x16x32_bf16(af, wb[ks], a1, 0, 0, 0);
          else        a0 = __builtin_amdgcn_mfma_f32_16x16x32_bf16(af, wb[ks], a0, 0, 0, 0);
        }
        s4 = a0 + a1;
        int bad = __builtin_isnan(s4[0]) | __builtin_isnan(s4[1]) |
                  __builtin_isnan(s4[2]) | __builtin_isnan(s4[3]);
        if (!__any(bad)) break;              // all sources were valid (non-sentinel)
      }
    }

    red[t & 1][w][lane] = s4;
    __syncthreads();                          // partials visible to wave 0

    if (w == 0) {
      floatx4 tot = red[t & 1][0][lane] + red[t & 1][1][lane] +
                    red[t & 1][2][lane] + red[t & 1][3][lane];
      float hv[4];
#pragma unroll
      for (int jj = 0; jj < 4; ++jj) {
        float s = tot[jj] + xi[jj];
        float e = __expf(2.0f * s);           // tanh = 1 - 2/(e^{2s}+1)
        hv[jj] = 1.0f - 2.0f * __builtin_amdgcn_rcpf(e + 1.0f);
      }
      // pair-pack with lane^1 so each store is a full dword (2 adjacent outs)
      float pv[4];
#pragma unroll
      for (int jj = 0; jj < 4; ++jj) pv[jj] = __shfl_xor(hv[jj], 1);
      const int ev = (lane & 1) == 0;
      const int jA = ev ? 0 : 2, jB = ev ? 1 : 3;
      unsigned dA = ev ? ((unsigned)f2bf(hv[jA]) | ((unsigned)f2bf(pv[jA]) << 16))
                       : ((unsigned)f2bf(pv[jA]) | ((unsigned)f2bf(hv[jA]) << 16));
      unsigned dB = ev ? ((unsigned)f2bf(hv[jB]) | ((unsigned)f2bf(pv[jB]) << 16))
                       : ((unsigned)f2bf(pv[jB]) | ((unsigned)f2bf(hv[jB]) << 16));
      unsigned* rowA = (unsigned*)&hst[(size_t)t * 16384 + (size_t)(g * 4 + jA) * 1024 + out_base + (n & ~1)];
      unsigned* rowB = (unsigned*)&hst[(size_t)t * 16384 + (size_t)(g * 4 + jB) * 1024 + out_base + (n & ~1)];
      __hip_atomic_store(rowA, dA, __ATOMIC_RELAXED, __HIP_MEMORY_SCOPE_AGENT);
      __hip_atomic_store(rowB, dB, __ATOMIC_RELAXED, __HIP_MEMORY_SCOPE_AGENT);
    }
  }
}

// ---------------- host launch ----------------
extern "C" void kernel_launch(void* const* d_in, const int* in_sizes, int n_in,
                              void* d_out, int out_size, void* d_ws, size_t ws_size,
                              hipStream_t stream) {
  const int*   ids  = (const int*)d_in[0];     // [16,256]
  const float* emb  = (const float*)d_in[1];   // [32000,1024]
  const float* w_hx = (const float*)d_in[2];   // [1024,1024]
  const float* w_hh = (const float*)d_in[3];   // [1024,1024]
  const float* w_yh = (const float*)d_in[4];   // [32000,1024]
  float*       out  = (float*)d_out;           // [16,256,32000]

  const int B = 16, S = 256, H = 1024, V = 32000;
  const int BS = B * S;

  char*  ws  = (char*)d_ws;
  size_t off = 0;
  auto alloc = [&](size_t bytes) {
    size_t cur = off;
    off += (bytes + 255) & ~(size_t)255;
    return (void*)(ws + cur);
  };

  unsigned short* whx_bf = (unsigned short*)alloc((size_t)H * H * 2);
  unsigned short* whh_bf = (unsigned short*)alloc((size_t)H * H * 2);
  unsigned short* wyh_bf = (unsigned short*)alloc((size_t)V * H * 2);
  unsigned short* x_bf   = (unsigned short*)alloc((size_t)BS * H * 2);
  float*          xin    = (float*)alloc((size_t)BS * H * 4);   // [t*16+b][H]
  unsigned short* hst    = (unsigned short*)alloc((size_t)BS * H * 2); // [t][b][H]
  int*            dflag  = (int*)alloc(256);

  // NaN-arm the step buffer every call (write-once data-as-flag; replay-safe).
  hipMemsetAsync(hst, 0xFF, (size_t)BS * H * 2, stream);
  hipMemsetAsync(dflag, 0, 256, stream);

  detect_i64<<<dim3(1), dim3(256), 0, stream>>>(ids, dflag);
  convert_bf16<<<dim3((H * H) / 1024), dim3(256), 0, stream>>>(w_hx, whx_bf, H * H);
  convert_bf16<<<dim3((H * H) / 1024), dim3(256), 0, stream>>>(w_hh, whh_bf, H * H);
  convert_bf16<<<dim3((V * H) / 1024), dim3(256), 0, stream>>>(w_yh, wyh_bf, V * H);
  gather_embed<<<dim3(BS), dim3(256), 0, stream>>>(ids, emb, x_bf, dflag);

  // xin[s*16+b] = x[b*256+s] @ w_hx^T : rowmap=1
  gemm_bt<<<dim3((BS / 128) * (H / 128)), dim3(256), 0, stream>>>(x_bf, whx_bf, xin, BS, H, H, 1);

  // sequential recurrence: 64 WGs x 4 waves, MFMA, data-as-flag(NaN) sync
  rnn_mfma<<<dim3(64), dim3(256), 0, stream>>>(xin, whh_bf, hst);

  // logits[b*256+t] = h[t*16+b] @ w_yh^T : rowmap=2
  gemm_bt<<<dim3((BS / 128) * (V / 128)), dim3(256), 0, stream>>>(hst, wyh_bf, out, BS, V, H, 2);
}